// Round 2
// baseline (98.249 us; speedup 1.0000x reference)
//
#include <hip/hip_runtime.h>
#include <hip/hip_bf16.h>

namespace {

constexpr int MM = 64;
constexpr int KK = 4096;
constexpr int NN = 11008;
constexpr int NZROW = NN / 8;       // 1376
constexpr int BN = 128;             // cols per block = 4 waves x 32
constexpr int KSPLIT = 8;
constexpr int KSEG = KK / KSPLIT;   // 512
constexpr int NTILES = NN / BN;     // 86
constexpr int BK = 32;              // k per chunk (one MFMA K)
constexpr int NCH = KSEG / BK;      // 16 chunks
constexpr int GCH = 4;              // chunks per A-stage group (128 k)
constexpr int NG = NCH / GCH;       // 4 groups
constexpr int AROWI = 68;           // ints per A row: 64 data (128 bf16) + 4 pad
constexpr int ABUFI = MM * AROWI;   // 4352 ints per buffer (17.4 KB)
constexpr size_t WS_NEED = (size_t)KSPLIT * MM * NN * 4;  // 22.5 MB partials

static_assert(NCH % GCH == 0, "groups must tile chunks");

typedef float f32x4 __attribute__((ext_vector_type(4)));
typedef short s16x8 __attribute__((ext_vector_type(8)));
typedef int   i32x4 __attribute__((ext_vector_type(4)));
typedef int   i32x2 __attribute__((ext_vector_type(2)));

__device__ __forceinline__ int pack_bf16(float a, float b) {
  union { __hip_bfloat162 h; int i; } u;
  u.h.x = __float2bfloat16(a);
  u.h.y = __float2bfloat16(b);
  return u.i;
}

// fallback path only: out[m][n] = bias[n], atomics on top
__global__ __launch_bounds__(256) void prep_kernel(
    const float* __restrict__ bias, float* __restrict__ out)
{
  const int i = blockIdx.x * 256 + threadIdx.x;
  out[i] = bias[i % NN];
}

// ws path: out = bias + sum of KSPLIT partials
__global__ __launch_bounds__(256) void reduce_kernel(
    const float* __restrict__ ws, const float* __restrict__ bias,
    float* __restrict__ out)
{
  const int i4 = (blockIdx.x * 256 + threadIdx.x) * 4;
  f32x4 acc = *(const f32x4*)(bias + (i4 % NN));
  #pragma unroll
  for (int s = 0; s < KSPLIT; ++s)
    acc += *(const f32x4*)(ws + (size_t)s * (MM * NN) + i4);
  *(f32x4*)(out + i4) = acc;
}

// R7 (resubmit after infra failure): register-direct B. One qweight dword =
// 8 consecutive k of one column = exactly one MFMA 16x16x32 B-fragment for
// lane (c,quad). So B is dequantized qw->VGPR->MFMA with ZERO LDS traffic
// and no staging barrier. Each wave owns 32 cols (2 col-tiles) x all 64
// rows (4 row-tiles) = 8 acc. Only A goes through LDS (bf16, 64 rows x
// 128 k per group, double-buffered) -> one barrier per 4 chunks instead of
// per chunk; LDS traffic cut ~3x. Dequant numerics identical to R6:
// qf = (nib|0x4B000000) = 2^23+q exactly, C = 2^23+z+1 by integer add on
// the 2^23 bit pattern, (qf-C) exact, single rounding in s*d.
template<bool ATOMIC>
__global__ __launch_bounds__(256, 4) void gptq_gemm_kernel(
    const float* __restrict__ x, const int* __restrict__ qw,
    const int* __restrict__ qz, const float* __restrict__ scales,
    float* __restrict__ out)
{
  __shared__ int As[2 * ABUFI];   // 34.8 KB, A only

  const int tid  = threadIdx.x;
  const int wave = tid >> 6;
  const int lane = tid & 63;
  const int c    = lane & 15;
  const int quad = lane >> 4;

  const int ks     = blockIdx.x & 7;
  const int ntile  = blockIdx.x >> 3;
  const int n0     = ntile * BN;
  const int kbase0 = ks * KSEG;
  const int grp0   = kbase0 >> 7;          // scale-group base = ks*4

  const int ncol = n0 + wave * 32 + c;     // t=0 col; t=1 is ncol+16

  // A staging: per load j, a wave covers 2 rows x 512B contiguous (coalesced).
  // row = wave*16 + j*2 + (lane>>5), k-offset = (lane&31)*4 within the group.
  const int arow0 = wave * 16 + (lane >> 5);
  const float* xp0 = x + (size_t)arow0 * KK + kbase0 + (lane & 31) * 4;

  // B pointer: row (kbase0/8 + quad), col ncol; chunk i advances rows by 4.
  const int* qwb = qw + ((size_t)(kbase0 >> 3) + quad) * NN + ncol;

  f32x4 acc[8];   // acc[r*2+t]
  #pragma unroll
  for (int t = 0; t < 8; ++t) acc[t] = {0.f, 0.f, 0.f, 0.f};

  f32x4 S[8];            // in-flight x group (issued 4 chunks early)
  int   pB0[4], pB1[4];  // qweight ring, depth-3 (cold HBM stream)
  float pS0[2], pS1[2];  // scales, next-group prefetch (L2-warm)
  int   pZ0[2], pZ1[2];  // qzeros
  float s0, s1, C0, C1;  // current-group dequant constants

  auto stage_load = [&](int g) {
    const float* xp = xp0 + g * 128;
    #pragma unroll
    for (int j = 0; j < 8; ++j)
      S[j] = *(const f32x4*)(xp + (size_t)j * 2 * KK);
  };
  auto stage_write = [&](int g) {
    int* Ab = As + (g & 1) * ABUFI + arow0 * AROWI + (lane & 31) * 2;
    #pragma unroll
    for (int j = 0; j < 8; ++j) {
      i32x2 w2;
      w2.x = pack_bf16(S[j].x, S[j].y);
      w2.y = pack_bf16(S[j].z, S[j].w);
      *(i32x2*)&Ab[j * 2 * AROWI] = w2;
    }
  };
  auto pfB = [&](int i) {
    const int* qp = qwb + (size_t)i * 4 * NN;
    pB0[i & 3] = qp[0];
    pB1[i & 3] = qp[16];
  };
  auto pfS = [&](int g) {
    const int sl = g & 1;
    const float* sp = scales + (size_t)(grp0 + g) * NN + ncol;
    pS0[sl] = sp[0];
    pS1[sl] = sp[16];
    const int* zp = qz + (size_t)(grp0 + g) * NZROW + (ncol >> 3);
    pZ0[sl] = zp[0];
    pZ1[sl] = zp[2];   // (ncol+16)>>3 == (ncol>>3)+2
  };
  auto setSC = [&](int g) {
    const int sl = g & 1;
    const int sh = (ncol & 7) * 4;       // same nibble for ncol and ncol+16
    s0 = pS0[sl];
    s1 = pS1[sl];
    C0 = __int_as_float(0x4B000000 + ((pZ0[sl] >> sh) & 15) + 1);
    C1 = __int_as_float(0x4B000000 + ((pZ1[sl] >> sh) & 15) + 1);
  };
  auto dq8 = [&](int v, float s, float C) -> i32x4 {
    i32x4 p;
    p.x = pack_bf16(s * (__int_as_float(((v      ) & 15) | 0x4B000000) - C),
                    s * (__int_as_float(((v >>  4) & 15) | 0x4B000000) - C));
    p.y = pack_bf16(s * (__int_as_float(((v >>  8) & 15) | 0x4B000000) - C),
                    s * (__int_as_float(((v >> 12) & 15) | 0x4B000000) - C));
    p.z = pack_bf16(s * (__int_as_float(((v >> 16) & 15) | 0x4B000000) - C),
                    s * (__int_as_float(((v >> 20) & 15) | 0x4B000000) - C));
    p.w = pack_bf16(s * (__int_as_float(((v >> 24) & 15) | 0x4B000000) - C),
                    s * (__int_as_float(((v >> 28) & 15) | 0x4B000000) - C));
    return p;
  };

  // ---- prologue ----
  pfS(0);
  stage_load(0);
  pfB(0); pfB(1); pfB(2);
  stage_write(0);
  // LDS-only barrier: leaves prefetch vmcnt in flight (pattern verified in R5/R6)
  __asm__ volatile("s_waitcnt lgkmcnt(0)\n\ts_barrier" ::: "memory");
  setSC(0);
  pfS(1);

  #pragma unroll
  for (int i = 0; i < NCH; ++i) {
    const int g = i >> 2, cc = i & 3, buf = g & 1;
    if (cc == 0 && g + 1 < NG) stage_load(g + 1);   // 4 chunks of latency cover
    if (i + 3 < NCH) pfB(i + 3);                    // deep qw prefetch

    // B: dequant straight into MFMA B fragments (no LDS)
    union { i32x4 i4; s16x8 s8; } u0, u1;
    u0.i4 = dq8(pB0[i & 3], s0, C0);
    u1.i4 = dq8(pB1[i & 3], s1, C1);

    // A: bf16 fragments from LDS (stride 68 ints -> even 8-lane/bank-group b128)
    const int* Ab = As + buf * ABUFI;
    const int aoff = c * AROWI + cc * 16 + quad * 4;
    const s16x8 af0 = *(const s16x8*)&Ab[aoff];
    const s16x8 af1 = *(const s16x8*)&Ab[aoff + 16 * AROWI];
    const s16x8 af2 = *(const s16x8*)&Ab[aoff + 32 * AROWI];
    const s16x8 af3 = *(const s16x8*)&Ab[aoff + 48 * AROWI];

    acc[0] = __builtin_amdgcn_mfma_f32_16x16x32_bf16(af0, u0.s8, acc[0], 0, 0, 0);
    acc[1] = __builtin_amdgcn_mfma_f32_16x16x32_bf16(af0, u1.s8, acc[1], 0, 0, 0);
    acc[2] = __builtin_amdgcn_mfma_f32_16x16x32_bf16(af1, u0.s8, acc[2], 0, 0, 0);
    acc[3] = __builtin_amdgcn_mfma_f32_16x16x32_bf16(af1, u1.s8, acc[3], 0, 0, 0);
    acc[4] = __builtin_amdgcn_mfma_f32_16x16x32_bf16(af2, u0.s8, acc[4], 0, 0, 0);
    acc[5] = __builtin_amdgcn_mfma_f32_16x16x32_bf16(af2, u1.s8, acc[5], 0, 0, 0);
    acc[6] = __builtin_amdgcn_mfma_f32_16x16x32_bf16(af3, u0.s8, acc[6], 0, 0, 0);
    acc[7] = __builtin_amdgcn_mfma_f32_16x16x32_bf16(af3, u1.s8, acc[7], 0, 0, 0);

    if (cc == 3 && g + 1 < NG) {
      // write next A buffer (buf^1: its last readers drained before our
      // entry barrier, so write-before-barrier is race-free), then sync.
      stage_write(g + 1);
      __asm__ volatile("s_waitcnt lgkmcnt(0)\n\ts_barrier" ::: "memory");
      setSC(g + 1);
      if (g + 2 < NG) pfS(g + 2);
    }
  }

  // ---- epilogue: rows r*16 + quad*4 + j, cols ncol + t*16 ----
  if (ATOMIC) {
    #pragma unroll
    for (int r = 0; r < 4; ++r) {
      #pragma unroll
      for (int t = 0; t < 2; ++t) {
        const f32x4 a = acc[r * 2 + t];
        float* op = out + (size_t)(r * 16 + quad * 4) * NN + ncol + t * 16;
        atomicAdd(&op[0],          a.x);
        atomicAdd(&op[NN],         a.y);
        atomicAdd(&op[2 * NN],     a.z);
        atomicAdd(&op[3 * NN],     a.w);
      }
    }
  } else {
    float* wsp = out + (size_t)ks * (MM * NN);
    #pragma unroll
    for (int r = 0; r < 4; ++r) {
      #pragma unroll
      for (int t = 0; t < 2; ++t) {
        const f32x4 a = acc[r * 2 + t];
        float* op = wsp + (size_t)(r * 16 + quad * 4) * NN + ncol + t * 16;
        op[0]      = a.x;
        op[NN]     = a.y;
        op[2 * NN] = a.z;
        op[3 * NN] = a.w;
      }
    }
  }
}

} // namespace

extern "C" void kernel_launch(void* const* d_in, const int* in_sizes, int n_in,
                              void* d_out, int out_size, void* d_ws, size_t ws_size,
                              hipStream_t stream) {
  const float* x      = (const float*)d_in[0];
  const int*   qw     = (const int*)d_in[1];
  const int*   qz     = (const int*)d_in[2];
  const float* scales = (const float*)d_in[3];
  const float* bias   = (const float*)d_in[4];
  float* out = (float*)d_out;

  if (ws_size >= WS_NEED) {
    float* ws = (float*)d_ws;
    gptq_gemm_kernel<false><<<NTILES * KSPLIT, 256, 0, stream>>>(x, qw, qz, scales, ws);
    reduce_kernel<<<(MM * NN) / 1024, 256, 0, stream>>>(ws, bias, out);
  } else {
    prep_kernel<<<(MM * NN) / 256, 256, 0, stream>>>(bias, out);
    gptq_gemm_kernel<true><<<NTILES * KSPLIT, 256, 0, stream>>>(x, qw, qz, scales, out);
  }
}